// Round 1
// 5578.412 us; speedup vs baseline: 1.4206x; 1.4206x over previous
//
#include <hip/hip_runtime.h>
#include <hip/hip_bf16.h>

using bf16 = __hip_bfloat16;

#define EDGES 25000
#define NNODES 5000
#define EPB 4
#define NBLK (EDGES / EPB)

__device__ __forceinline__ float sigmf(float x) { return 1.0f / (1.0f + expf(-x)); }

template<bool BF>
__device__ __forceinline__ float LD1(const void* p, size_t i) {
    if (BF) return __bfloat162float(((const bf16*)p)[i]);
    else    return ((const float*)p)[i];
}

template<bool BF>
__device__ __forceinline__ float4 LD4(const void* p, size_t i) {
    if (BF) {
        ushort4 u = *reinterpret_cast<const ushort4*>((const bf16*)p + i);
        float4 r;
        r.x = __uint_as_float((unsigned)u.x << 16);
        r.y = __uint_as_float((unsigned)u.y << 16);
        r.z = __uint_as_float((unsigned)u.z << 16);
        r.w = __uint_as_float((unsigned)u.w << 16);
        return r;
    } else {
        return *reinterpret_cast<const float4*>((const float*)p + i);
    }
}

__device__ __forceinline__ void fma4(float4& a, float s, const float4& w) {
    a.x += s * w.x; a.y += s * w.y; a.z += s * w.z; a.w += s * w.w;
}

__device__ __forceinline__ void silu4(float4& a) {
    a.x *= sigmf(a.x); a.y *= sigmf(a.y); a.z *= sigmf(a.z); a.w *= sigmf(a.w);
}

// monotone float<->uint encoding for atomicMax on floats
__device__ __forceinline__ unsigned encF(float f) {
    unsigned b = __float_as_uint(f);
    return (b & 0x80000000u) ? ~b : (b | 0x80000000u);
}
__device__ __forceinline__ float decF(unsigned e) {
    unsigned b = (e & 0x80000000u) ? (e ^ 0x80000000u) : ~e;
    return __uint_as_float(b);
}
#define ENC_NEGINF 0x007FFFFFu

// ---------------- dtype detector ----------------
__global__ void k_detect(const void* edge_dist, int* flag) {
    if (threadIdx.x == 0 && blockIdx.x == 0) {
        const bf16* p = (const bf16*)edge_dist;
        int ok = 1;
        for (int i = 0; i < 256; i++) {
            float v = __bfloat162float(p[i]);
            if (!(v >= 0.0f && v <= 1.0f)) { ok = 0; break; }
        }
        *flag = ok;
    }
}

// ---------------- fill ----------------
__global__ void k_fill(float* accb, float* nden, unsigned* nmax) {
    int tid = blockIdx.x * 256 + threadIdx.x;
    if (tid < NNODES * 1600) accb[tid] = 0.0f;
    if (tid < NNODES * 8) { nden[tid] = 0.0f; nmax[tid] = ENC_NEGINF; }
}

// ---------------- alpha prepass (unchanged this round) ----------------
// sm layout (floats): X@0(3200) wg5@3200(128) x0@3328(640) extraA@3968(256)
// xe@4224(192) t1@4416 h1@4480 t2@4544 h2@4608 rad0@4672(640) -> 5312
template<bool BF>
__global__ __launch_bounds__(256) void k_alpha(
    const void* __restrict__ node_feats, const void* __restrict__ edge_dist,
    const void* __restrict__ wigner, const void* __restrict__ emb_s,
    const void* __restrict__ emb_r,
    const void* __restrict__ rw1, const void* __restrict__ rb1,
    const void* __restrict__ rl1s, const void* __restrict__ rl1b,
    const void* __restrict__ rw2, const void* __restrict__ rb2,
    const void* __restrict__ rl2s, const void* __restrict__ rl2b,
    const void* __restrict__ rw3, const void* __restrict__ rb3,
    const void* __restrict__ c1w0, const void* __restrict__ c1b0,
    const void* __restrict__ an_s, const void* __restrict__ an_b,
    const void* __restrict__ adot,
    const int* __restrict__ species, const int* __restrict__ senders,
    const int* __restrict__ receivers, const int* __restrict__ dtf,
    float* __restrict__ alpha_out, unsigned* __restrict__ nmax)
{
    if ((*dtf != 0) != BF) return;
    __shared__ __align__(16) float sm[5312];
    float* X = sm;
    float* wg5 = sm + 3200;
    float* x0 = sm + 3328;
    float* extraA = sm + 3968;
    float* xe = sm + 4224;
    float* t1 = sm + 4416;
    float* h1 = sm + 4480;
    float* t2 = sm + 4544;
    float* h2 = sm + 4608;
    float* rad0 = sm + 4672;

    const int e = blockIdx.x, t = threadIdx.x;
    const int snd = senders[e], rcv = receivers[e];

    for (int i = t; i < 192; i += 256) {
        float v;
        if (i < 64)       v = LD1<BF>(edge_dist, (size_t)e * 64 + i);
        else if (i < 128) v = LD1<BF>(emb_s, (size_t)species[snd] * 64 + (i - 64));
        else              v = LD1<BF>(emb_r, (size_t)species[rcv] * 64 + (i - 128));
        xe[i] = v;
    }
    for (int q = t; q < 800; q += 256) {
        int k = q >> 5, c0 = (q & 31) * 4;
        float4 v = (c0 < 64) ? LD4<BF>(node_feats, (size_t)snd * 1600 + k * 64 + c0)
                             : LD4<BF>(node_feats, (size_t)rcv * 1600 + k * 64 + (c0 - 64));
        *(float4*)&X[q * 4] = v;
    }
    for (int i = t; i < 125; i += 256) wg5[i] = LD1<BF>(wigner, (size_t)e * 475 + i);
    __syncthreads();

    if (t < 64) {
        float acc = LD1<BF>(rb1, t);
        for (int k = 0; k < 192; k++) acc += xe[k] * LD1<BF>(rw1, k * 64 + t);
        t1[t] = acc;
    }
    __syncthreads();
    if (t < 64) {
        float mu = 0.0f;
        for (int k = 0; k < 64; k++) mu += t1[k];
        mu *= (1.0f / 64.0f);
        float var = 0.0f;
        for (int k = 0; k < 64; k++) { float d = t1[k] - mu; var += d * d; }
        float xn = (t1[t] - mu) * rsqrtf(var * (1.0f / 64.0f) + 1e-6f) * LD1<BF>(rl1s, t) + LD1<BF>(rl1b, t);
        h1[t] = xn * sigmf(xn);
    }
    __syncthreads();
    if (t < 64) {
        float acc = LD1<BF>(rb2, t);
        for (int k = 0; k < 64; k++) acc += h1[k] * LD1<BF>(rw2, k * 64 + t);
        t2[t] = acc;
    }
    __syncthreads();
    if (t < 64) {
        float mu = 0.0f;
        for (int k = 0; k < 64; k++) mu += t2[k];
        mu *= (1.0f / 64.0f);
        float var = 0.0f;
        for (int k = 0; k < 64; k++) { float d = t2[k] - mu; var += d * d; }
        float xn = (t2[t] - mu) * rsqrtf(var * (1.0f / 64.0f) + 1e-6f) * LD1<BF>(rl2s, t) + LD1<BF>(rl2b, t);
        h2[t] = xn * sigmf(xn);
    }
    __syncthreads();
    if (t < 160) {  // rad0: first 640 outputs of rad
        int j0 = t * 4;
        float4 acc = LD4<BF>(rb3, j0);
        for (int k = 0; k < 64; k++) fma4(acc, h2[k], LD4<BF>(rw3, (size_t)k * 1536 + j0));
        *(float4*)&rad0[j0] = acc;
    }
    __syncthreads();
    if (t < 160) {  // rotate rows 0..4 + rad scale
        int q = t, m = q >> 5, c0 = (q & 31) * 4;
        float4 acc = {0.f, 0.f, 0.f, 0.f};
        #pragma unroll
        for (int k = 0; k < 25; k++) fma4(acc, wg5[m * 25 + k], *(const float4*)&X[k * 128 + c0]);
        float4 rv = *(const float4*)&rad0[q * 4];
        acc.x *= rv.x; acc.y *= rv.y; acc.z *= rv.z; acc.w *= rv.w;
        *(float4*)&x0[q * 4] = acc;
    }
    __syncthreads();
    if (t < 64) {  // alpha cols [320,576) of conv1-m0
        int j0 = 320 + t * 4;
        float4 acc = LD4<BF>(c1b0, j0);
        for (int i = 0; i < 640; i++) fma4(acc, x0[i], LD4<BF>(c1w0, (size_t)i * 640 + j0));
        *(float4*)&extraA[t * 4] = acc;
    }
    __syncthreads();
    if (t < 8) {
        int h = t;
        float mu = 0.0f;
        for (int k = 0; k < 32; k++) mu += extraA[h * 32 + k];
        mu *= (1.0f / 32.0f);
        float var = 0.0f;
        for (int k = 0; k < 32; k++) { float d = extraA[h * 32 + k] - mu; var += d * d; }
        float rs = rsqrtf(var * (1.0f / 32.0f) + 1e-6f);
        float logit = 0.0f;
        for (int k = 0; k < 32; k++) {
            float xn = (extraA[h * 32 + k] - mu) * rs * LD1<BF>(an_s, k) + LD1<BF>(an_b, k);
            float slr = 0.6f * xn + 0.4f * xn * (2.0f * sigmf(xn) - 1.0f);
            logit += slr * LD1<BF>(adot, h * 32 + k);
        }
        alpha_out[e * 8 + h] = logit;
        atomicMax(&nmax[rcv * 8 + h], encF(logit));
    }
}

// ---------------- exp + denom ----------------
__global__ void k_exp(const int* __restrict__ receivers, const unsigned* __restrict__ nmax,
                      float* __restrict__ alpha, float* __restrict__ nden) {
    int tid = blockIdx.x * 256 + threadIdx.x;
    if (tid >= EDGES * 8) return;
    int e = tid >> 3, h = tid & 7;
    int r = receivers[e];
    float m = decF(nmax[r * 8 + h]);
    float ex = expf(alpha[tid] - m);
    alpha[tid] = ex;
    atomicAdd(&nden[r * 8 + h], ex);
}

// ---------------- mega2: 4 edges per block, weight loads amortized 4x -------
// LDS map (floats, total 19744 = 77.1 KB -> 2 blocks/CU):
//   Q   [0,9728)      : EF1[e][2432] (P2-P3) | g scratch (P4) | EF3[e][2432] (P5-P7)
//   C   [9728,14592)  : P1 scratch | P2 X(3200)+wg(480) | EF2[e][1216] (P3-P4)
//                       | P5 y-staging | P7 WV[e][480]
//   RAD [13408,19552) : radial out [e][1536] (live P1-P2 only; overlays C-tail/YF/GAT)
//   YF  [14592,19456) : P3 y-staging | FEATS[e][1216] (P4-P5) | P7 EO tail
//   GAT [19456,19712) : gating [e][64] (P3-P4)
//   ALs [19712,19744) : alpha scale [e][8] (P7)
template<bool BF>
__global__ __launch_bounds__(256, 2) void k_mega2(
    const void* __restrict__ node_feats, const void* __restrict__ edge_dist,
    const void* __restrict__ wigner, const void* __restrict__ wigner_inv,
    const void* __restrict__ to_grid, const void* __restrict__ from_grid,
    const void* __restrict__ emb_s, const void* __restrict__ emb_r,
    const void* __restrict__ rw1, const void* __restrict__ rb1,
    const void* __restrict__ rl1s, const void* __restrict__ rl1b,
    const void* __restrict__ rw2, const void* __restrict__ rb2,
    const void* __restrict__ rl2s, const void* __restrict__ rl2b,
    const void* __restrict__ rw3, const void* __restrict__ rb3,
    const void* __restrict__ c1w0, const void* __restrict__ c1b0,
    const void* __restrict__ c1w1, const void* __restrict__ c1w2,
    const void* __restrict__ c2w0, const void* __restrict__ c2b0,
    const void* __restrict__ c2w1, const void* __restrict__ c2w2,
    const void* __restrict__ proj_w,
    const int* __restrict__ species, const int* __restrict__ senders,
    const int* __restrict__ receivers, const int* __restrict__ dtf,
    const float* __restrict__ alpha, const float* __restrict__ nden,
    float* __restrict__ accb)
{
    if ((*dtf != 0) != BF) return;
    __shared__ __align__(16) float sm[19744];
    float* Q   = sm;
    float* C   = sm + 9728;
    float* RAD = sm + 13408;
    float* YF  = sm + 14592;
    float* GAT = sm + 19456;
    float* ALs = sm + 19712;

    const int t = threadIdx.x;
    const int e0 = blockIdx.x * EPB;
    int snd[EPB], rcv[EPB];
    #pragma unroll
    for (int e = 0; e < EPB; e++) { snd[e] = senders[e0 + e]; rcv[e] = receivers[e0 + e]; }

    // ---- P1: radial MLP (weights shared across 4 edges) ----
    {
        float* XE = C;
        float* T1 = C + 768;
        float* H1 = C + 1024;
        float* T2 = C + 1280;
        float* H2 = C + 1536;

        #pragma unroll
        for (int e = 0; e < EPB; e++)
            for (int i = t; i < 192; i += 256) {
                float v;
                if (i < 64)       v = LD1<BF>(edge_dist, (size_t)(e0 + e) * 64 + i);
                else if (i < 128) v = LD1<BF>(emb_s, (size_t)species[snd[e]] * 64 + (i - 64));
                else              v = LD1<BF>(emb_r, (size_t)species[rcv[e]] * 64 + (i - 128));
                XE[e * 192 + i] = v;
            }
        __syncthreads();
        if (t < 64) {
            float acc[EPB];
            float b = LD1<BF>(rb1, t);
            #pragma unroll
            for (int e = 0; e < EPB; e++) acc[e] = b;
            for (int k = 0; k < 192; k++) {
                float w = LD1<BF>(rw1, k * 64 + t);
                #pragma unroll
                for (int e = 0; e < EPB; e++) acc[e] += XE[e * 192 + k] * w;
            }
            #pragma unroll
            for (int e = 0; e < EPB; e++) T1[e * 64 + t] = acc[e];
        }
        __syncthreads();
        if (t < 64) {
            float s = LD1<BF>(rl1s, t), b = LD1<BF>(rl1b, t);
            #pragma unroll
            for (int e = 0; e < EPB; e++) {
                float mu = 0.f;
                for (int k = 0; k < 64; k++) mu += T1[e * 64 + k];
                mu *= (1.f / 64.f);
                float var = 0.f;
                for (int k = 0; k < 64; k++) { float d = T1[e * 64 + k] - mu; var += d * d; }
                float xn = (T1[e * 64 + t] - mu) * rsqrtf(var * (1.f / 64.f) + 1e-6f) * s + b;
                H1[e * 64 + t] = xn * sigmf(xn);
            }
        }
        __syncthreads();
        if (t < 64) {
            float acc[EPB];
            float b = LD1<BF>(rb2, t);
            #pragma unroll
            for (int e = 0; e < EPB; e++) acc[e] = b;
            for (int k = 0; k < 64; k++) {
                float w = LD1<BF>(rw2, k * 64 + t);
                #pragma unroll
                for (int e = 0; e < EPB; e++) acc[e] += H1[e * 64 + k] * w;
            }
            #pragma unroll
            for (int e = 0; e < EPB; e++) T2[e * 64 + t] = acc[e];
        }
        __syncthreads();
        if (t < 64) {
            float s = LD1<BF>(rl2s, t), b = LD1<BF>(rl2b, t);
            #pragma unroll
            for (int e = 0; e < EPB; e++) {
                float mu = 0.f;
                for (int k = 0; k < 64; k++) mu += T2[e * 64 + k];
                mu *= (1.f / 64.f);
                float var = 0.f;
                for (int k = 0; k < 64; k++) { float d = T2[e * 64 + k] - mu; var += d * d; }
                float xn = (T2[e * 64 + t] - mu) * rsqrtf(var * (1.f / 64.f) + 1e-6f) * s + b;
                H2[e * 64 + t] = xn * sigmf(xn);
            }
        }
        __syncthreads();
        for (int qq = t; qq < 384; qq += 256) {
            int j0 = qq * 4;
            float4 acc[EPB];
            float4 bv = LD4<BF>(rb3, j0);
            #pragma unroll
            for (int e = 0; e < EPB; e++) acc[e] = bv;
            for (int k = 0; k < 64; k++) {
                float4 w = LD4<BF>(rw3, (size_t)k * 1536 + j0);
                #pragma unroll
                for (int e = 0; e < EPB; e++) fma4(acc[e], H2[e * 64 + k], w);
            }
            #pragma unroll
            for (int e = 0; e < EPB; e++) *(float4*)&RAD[e * 1536 + j0] = acc[e];
        }
        __syncthreads();
    }

    // ---- P2: gather + wigner rotate + rad scale (per edge sequential) ----
    {
        float* X  = C;          // 3200
        float* WG = C + 3200;   // 480
        for (int e = 0; e < EPB; e++) {
            int s_ = senders[e0 + e], r_ = receivers[e0 + e];
            for (int q = t; q < 800; q += 256) {
                int k = q >> 5, c0 = (q & 31) * 4;
                float4 v = (c0 < 64) ? LD4<BF>(node_feats, (size_t)s_ * 1600 + k * 64 + c0)
                                     : LD4<BF>(node_feats, (size_t)r_ * 1600 + k * 64 + (c0 - 64));
                *(float4*)&X[q * 4] = v;
            }
            for (int i = t; i < 475; i += 256) WG[i] = LD1<BF>(wigner, (size_t)(e0 + e) * 475 + i);
            __syncthreads();
            for (int q = t; q < 608; q += 256) {
                int m = q >> 5, c0 = (q & 31) * 4;
                float4 acc = make_float4(0.f, 0.f, 0.f, 0.f);
                #pragma unroll
                for (int k = 0; k < 25; k++) fma4(acc, WG[m * 25 + k], *(const float4*)&X[k * 128 + c0]);
                int ri0;
                if (m < 5)       ri0 = m * 128 + c0;
                else if (m < 13) ri0 = 640 + ((m - 5) & 3) * 128 + c0;
                else             ri0 = 1152 + ((m - 13) % 3) * 128 + c0;
                float4 rv = *(const float4*)&RAD[e * 1536 + ri0];
                acc.x *= rv.x; acc.y *= rv.y; acc.z *= rv.z; acc.w *= rv.w;
                *(float4*)&Q[e * 2432 + q * 4] = acc;
            }
            __syncthreads();
        }
    }

    // ---- P3: conv1 (weights shared across 4 edges) ----
    float4 ra[EPB], rb[EPB];
    {
        float* EF2 = C;
        // m0 (threads 0..95: cols [0,320)+[576,640)) || m1 (threads 128..255)
        if (t < 96) {
            int jq = (t < 80) ? t : (144 + (t - 80));
            int j0 = jq * 4;
            float4 acc[EPB];
            float4 bv = LD4<BF>(c1b0, j0);
            #pragma unroll
            for (int e = 0; e < EPB; e++) acc[e] = bv;
            for (int i = 0; i < 640; i++) {
                float4 w = LD4<BF>(c1w0, (size_t)i * 640 + j0);
                #pragma unroll
                for (int e = 0; e < EPB; e++) fma4(acc[e], Q[e * 2432 + i], w);
            }
            if (t < 80) {
                #pragma unroll
                for (int e = 0; e < EPB; e++) *(float4*)&EF2[e * 1216 + j0] = acc[e];
            } else {
                #pragma unroll
                for (int e = 0; e < EPB; e++) *(float4*)&GAT[e * 64 + (t - 80) * 4] = acc[e];
            }
        } else if (t >= 128) {
            int j0 = (t - 128) * 4;  // 0..508
            #pragma unroll
            for (int e = 0; e < EPB; e++) { ra[e] = make_float4(0,0,0,0); rb[e] = make_float4(0,0,0,0); }
            for (int i = 0; i < 512; i++) {
                float4 w = LD4<BF>(c1w1, (size_t)i * 512 + j0);
                #pragma unroll
                for (int e = 0; e < EPB; e++) {
                    fma4(ra[e], Q[e * 2432 + 640 + i], w);
                    fma4(rb[e], Q[e * 2432 + 1152 + i], w);
                }
            }
            if (j0 >= 256) {  // threads 192..255 stage upper halves
                #pragma unroll
                for (int e = 0; e < EPB; e++) {
                    *(float4*)&YF[e * 256 + (j0 - 256)] = ra[e];
                    *(float4*)&YF[1024 + e * 256 + (j0 - 256)] = rb[e];
                }
            }
        }
        __syncthreads();
        if (t >= 128 && t < 192) {  // m1 combine (j0 < 256)
            int j0 = (t - 128) * 4;
            #pragma unroll
            for (int e = 0; e < EPB; e++) {
                float4 y0u = *(const float4*)&YF[e * 256 + j0];
                float4 y1u = *(const float4*)&YF[1024 + e * 256 + j0];
                float4 r, im;
                r.x = ra[e].x - y1u.x; r.y = ra[e].y - y1u.y; r.z = ra[e].z - y1u.z; r.w = ra[e].w - y1u.w;
                im.x = rb[e].x + y0u.x; im.y = rb[e].y + y0u.y; im.z = rb[e].z + y0u.z; im.w = rb[e].w + y0u.w;
                *(float4*)&EF2[e * 1216 + 320 + j0] = r;
                *(float4*)&EF2[e * 1216 + 576 + j0] = im;
            }
        }
        __syncthreads();
        // m2 (threads 0..95)
        if (t < 96) {
            int j0 = t * 4;  // 0..380
            #pragma unroll
            for (int e = 0; e < EPB; e++) { ra[e] = make_float4(0,0,0,0); rb[e] = make_float4(0,0,0,0); }
            for (int i = 0; i < 384; i++) {
                float4 w = LD4<BF>(c1w2, (size_t)i * 384 + j0);
                #pragma unroll
                for (int e = 0; e < EPB; e++) {
                    fma4(ra[e], Q[e * 2432 + 1664 + i], w);
                    fma4(rb[e], Q[e * 2432 + 2048 + i], w);
                }
            }
            if (j0 >= 192) {  // threads 48..95 stage upper halves
                #pragma unroll
                for (int e = 0; e < EPB; e++) {
                    *(float4*)&YF[e * 192 + (j0 - 192)] = ra[e];
                    *(float4*)&YF[768 + e * 192 + (j0 - 192)] = rb[e];
                }
            }
        }
        __syncthreads();
        if (t < 48) {  // m2 combine
            int j0 = t * 4;
            #pragma unroll
            for (int e = 0; e < EPB; e++) {
                float4 y0u = *(const float4*)&YF[e * 192 + j0];
                float4 y1u = *(const float4*)&YF[768 + e * 192 + j0];
                float4 r, im;
                r.x = ra[e].x - y1u.x; r.y = ra[e].y - y1u.y; r.z = ra[e].z - y1u.z; r.w = ra[e].w - y1u.w;
                im.x = rb[e].x + y0u.x; im.y = rb[e].y + y0u.y; im.z = rb[e].z + y0u.z; im.w = rb[e].w + y0u.w;
                *(float4*)&EF2[e * 1216 + 832 + j0] = r;
                *(float4*)&EF2[e * 1216 + 1024 + j0] = im;
            }
        }
        __syncthreads();
    }

    // ---- P4: grid nonlinearity (per edge sequential; tiny weights, L1-hot) ----
    {
        float* FE  = YF;   // FEATS [e][1216]
        float* G   = Q;    // 3200 scratch (EF1 dead)
        float* EF2 = C;
        for (int i = t; i < 4864; i += 256) FE[i] = 0.f;
        __syncthreads();
        for (int e = 0; e < EPB; e++) {
            for (int ch = 0; ch < 2; ch++) {
                int gbase = ch * 50;
                for (int q = t; q < 800; q += 256) {
                    int gi = q >> 4, c0 = (q & 15) * 4;
                    float4 acc = make_float4(0.f, 0.f, 0.f, 0.f);
                    #pragma unroll
                    for (int m = 0; m < 19; m++)
                        fma4(acc, LD1<BF>(to_grid, (gbase + gi) * 19 + m),
                             *(const float4*)&EF2[e * 1216 + m * 64 + c0]);
                    silu4(acc);
                    *(float4*)&G[q * 4] = acc;
                }
                __syncthreads();
                for (int q = t; q < 304; q += 256) {
                    int m = q >> 4, c0 = (q & 15) * 4;
                    float4 acc = *(const float4*)&FE[e * 1216 + q * 4];
                    for (int gi = 0; gi < 50; gi++)
                        fma4(acc, LD1<BF>(from_grid, (gbase + gi) * 19 + m),
                             *(const float4*)&G[gi * 64 + c0]);
                    *(float4*)&FE[e * 1216 + q * 4] = acc;
                }
                __syncthreads();
            }
        }
        if (t < 64) {
            #pragma unroll
            for (int e = 0; e < EPB; e++) { float x = GAT[e * 64 + t]; FE[e * 1216 + t] = x * sigmf(x); }
        }
        __syncthreads();
    }

    // ---- P5: conv2 -> EF3 (in Q; weights shared across 4 edges) ----
    {
        float* FE = YF;
        if (t < 160) {  // m0: 640 outs, k=320
            int j0 = t * 4;
            float4 acc[EPB];
            float4 bv = LD4<BF>(c2b0, j0);
            #pragma unroll
            for (int e = 0; e < EPB; e++) acc[e] = bv;
            for (int i = 0; i < 320; i++) {
                float4 w = LD4<BF>(c2w0, (size_t)i * 640 + j0);
                #pragma unroll
                for (int e = 0; e < EPB; e++) fma4(acc[e], FE[e * 1216 + i], w);
            }
            #pragma unroll
            for (int e = 0; e < EPB; e++) *(float4*)&Q[e * 2432 + j0] = acc[e];
        }
        {  // m1: 1024 cols, k=256, all threads
            int j0 = t * 4;
            #pragma unroll
            for (int e = 0; e < EPB; e++) { ra[e] = make_float4(0,0,0,0); rb[e] = make_float4(0,0,0,0); }
            for (int i = 0; i < 256; i++) {
                float4 w = LD4<BF>(c2w1, (size_t)i * 1024 + j0);
                #pragma unroll
                for (int e = 0; e < EPB; e++) {
                    fma4(ra[e], FE[e * 1216 + 320 + i], w);
                    fma4(rb[e], FE[e * 1216 + 576 + i], w);
                }
            }
            if (j0 >= 512) {
                #pragma unroll
                for (int e = 0; e < EPB; e++) {
                    *(float4*)&C[e * 512 + (j0 - 512)] = ra[e];
                    *(float4*)&C[2048 + e * 512 + (j0 - 512)] = rb[e];
                }
            }
        }
        __syncthreads();
        if (t < 128) {  // m1 combine
            int j0 = t * 4;
            #pragma unroll
            for (int e = 0; e < EPB; e++) {
                float4 y0u = *(const float4*)&C[e * 512 + j0];
                float4 y1u = *(const float4*)&C[2048 + e * 512 + j0];
                float4 r, im;
                r.x = ra[e].x - y1u.x; r.y = ra[e].y - y1u.y; r.z = ra[e].z - y1u.z; r.w = ra[e].w - y1u.w;
                im.x = rb[e].x + y0u.x; im.y = rb[e].y + y0u.y; im.z = rb[e].z + y0u.z; im.w = rb[e].w + y0u.w;
                *(float4*)&Q[e * 2432 + 640 + j0] = r;
                *(float4*)&Q[e * 2432 + 1152 + j0] = im;
            }
        }
        __syncthreads();
        if (t < 192) {  // m2: 768 cols, k=192
            int j0 = t * 4;
            #pragma unroll
            for (int e = 0; e < EPB; e++) { ra[e] = make_float4(0,0,0,0); rb[e] = make_float4(0,0,0,0); }
            for (int i = 0; i < 192; i++) {
                float4 w = LD4<BF>(c2w2, (size_t)i * 768 + j0);
                #pragma unroll
                for (int e = 0; e < EPB; e++) {
                    fma4(ra[e], FE[e * 1216 + 832 + i], w);
                    fma4(rb[e], FE[e * 1216 + 1024 + i], w);
                }
            }
            if (j0 >= 384) {
                #pragma unroll
                for (int e = 0; e < EPB; e++) {
                    *(float4*)&C[e * 384 + (j0 - 384)] = ra[e];
                    *(float4*)&C[1536 + e * 384 + (j0 - 384)] = rb[e];
                }
            }
        }
        __syncthreads();
        if (t < 96) {  // m2 combine
            int j0 = t * 4;
            #pragma unroll
            for (int e = 0; e < EPB; e++) {
                float4 y0u = *(const float4*)&C[e * 384 + j0];
                float4 y1u = *(const float4*)&C[1536 + e * 384 + j0];
                float4 r, im;
                r.x = ra[e].x - y1u.x; r.y = ra[e].y - y1u.y; r.z = ra[e].z - y1u.z; r.w = ra[e].w - y1u.w;
                im.x = rb[e].x + y0u.x; im.y = rb[e].y + y0u.y; im.z = rb[e].z + y0u.z; im.w = rb[e].w + y0u.w;
                *(float4*)&Q[e * 2432 + 1664 + j0] = r;
                *(float4*)&Q[e * 2432 + 2048 + j0] = im;
            }
        }
        __syncthreads();
    }

    // ---- P7: wigner_inv rotate + alpha + fused proj (proj_w shared 4x) ----
    {
        float* WV = C;           // [e][480]
        float* EO = C + 1920;    // [<=9][128][4]
        if (t < 32) {
            int e = t >> 3, h = t & 7;
            int ee = e0 + e;
            ALs[t] = alpha[(size_t)ee * 8 + h] / (nden[(size_t)receivers[ee] * 8 + h] + 1e-16f);
        }
        for (int i = t; i < 1900; i += 256) {
            int e = i / 475, j = i - e * 475;
            WV[e * 480 + j] = LD1<BF>(wigner_inv, (size_t)(e0 + e) * 475 + j);
        }
        __syncthreads();
        for (int kb = 0; kb < 25; kb += 9) {
            int nk = (kb + 9 <= 25) ? 9 : (25 - kb);
            for (int e = 0; e < EPB; e++) {
                for (int idx = t; idx < nk * 32; idx += 256) {
                    int ki = idx >> 5, c0 = (idx & 31) * 4;
                    int k = kb + ki;
                    float4 acc = make_float4(0.f, 0.f, 0.f, 0.f);
                    #pragma unroll
                    for (int m = 0; m < 19; m++)
                        fma4(acc, WV[e * 480 + k * 19 + m], *(const float4*)&Q[e * 2432 + m * 128 + c0]);
                    float al = ALs[e * 8 + (c0 >> 4)];
                    int b = (ki * 128 + c0) * 4 + e;
                    EO[b + 0]  = acc.x * al;
                    EO[b + 4]  = acc.y * al;
                    EO[b + 8]  = acc.z * al;
                    EO[b + 12] = acc.w * al;
                }
            }
            __syncthreads();
            if (t < nk * 16) {
                int ki = t >> 4, o0 = (t & 15) * 4;
                int k = kb + ki;
                int l = (k == 0) ? 0 : (k < 4) ? 1 : (k < 9) ? 2 : (k < 16) ? 3 : 4;
                float4 pa0 = make_float4(0,0,0,0), pa1 = pa0, pa2 = pa0, pa3 = pa0;
                const float* eob = &EO[ki * 512];
                for (int c = 0; c < 128; c++) {
                    float4 pw = LD4<BF>(proj_w, (size_t)l * 8192 + (size_t)c * 64 + o0);
                    float4 ev = *(const float4*)&eob[c * 4];
                    fma4(pa0, ev.x, pw); fma4(pa1, ev.y, pw);
                    fma4(pa2, ev.z, pw); fma4(pa3, ev.w, pw);
                }
                float* d0 = &accb[(size_t)rcv[0] * 1600 + k * 64 + o0];
                atomicAdd(d0 + 0, pa0.x); atomicAdd(d0 + 1, pa0.y);
                atomicAdd(d0 + 2, pa0.z); atomicAdd(d0 + 3, pa0.w);
                float* d1 = &accb[(size_t)rcv[1] * 1600 + k * 64 + o0];
                atomicAdd(d1 + 0, pa1.x); atomicAdd(d1 + 1, pa1.y);
                atomicAdd(d1 + 2, pa1.z); atomicAdd(d1 + 3, pa1.w);
                float* d2 = &accb[(size_t)rcv[2] * 1600 + k * 64 + o0];
                atomicAdd(d2 + 0, pa2.x); atomicAdd(d2 + 1, pa2.y);
                atomicAdd(d2 + 2, pa2.z); atomicAdd(d2 + 3, pa2.w);
                float* d3 = &accb[(size_t)rcv[3] * 1600 + k * 64 + o0];
                atomicAdd(d3 + 0, pa3.x); atomicAdd(d3 + 1, pa3.y);
                atomicAdd(d3 + 2, pa3.z); atomicAdd(d3 + 3, pa3.w);
            }
            __syncthreads();
        }
    }
}

// ---------------- bias + convert ----------------
template<bool BF>
__global__ void k_out(const float* __restrict__ accb, const void* __restrict__ proj_b,
                      void* __restrict__ out, const int* __restrict__ dtf) {
    if ((*dtf != 0) != BF) return;
    int i = blockIdx.x * 256 + threadIdx.x;
    if (i >= NNODES * 1600) return;
    int r = i % 1600;
    int m = r >> 6, o = r & 63;
    float v = accb[i] + ((m == 0) ? LD1<BF>(proj_b, o) : 0.0f);
    if (BF) ((bf16*)out)[i] = __float2bfloat16(v);
    else    ((float*)out)[i] = v;
}

extern "C" void kernel_launch(void* const* d_in, const int* in_sizes, int n_in,
                              void* d_out, int out_size, void* d_ws, size_t ws_size,
                              hipStream_t stream) {
    const void* node_feats = d_in[0];
    const void* edge_dist  = d_in[1];
    const void* wigner     = d_in[2];
    const void* wigner_inv = d_in[3];
    const void* to_grid    = d_in[4];
    const void* from_grid  = d_in[5];
    const void* emb_s      = d_in[6];
    const void* emb_r      = d_in[7];
    const void* rw1  = d_in[8];
    const void* rb1  = d_in[9];
    const void* rl1s = d_in[10];
    const void* rl1b = d_in[11];
    const void* rw2  = d_in[12];
    const void* rb2  = d_in[13];
    const void* rl2s = d_in[14];
    const void* rl2b = d_in[15];
    const void* rw3  = d_in[16];
    const void* rb3  = d_in[17];
    const void* c1w0 = d_in[18];
    const void* c1b0 = d_in[19];
    const void* c1w1 = d_in[20];
    const void* c1w2 = d_in[21];
    const void* c2w0 = d_in[22];
    const void* c2b0 = d_in[23];
    const void* c2w1 = d_in[24];
    const void* c2w2 = d_in[25];
    const void* an_s = d_in[26];
    const void* an_b = d_in[27];
    const void* adot = d_in[28];
    const void* proj_w = d_in[29];
    const void* proj_b = d_in[30];
    const int* species   = (const int*)d_in[31];
    const int* senders   = (const int*)d_in[32];
    const int* receivers = (const int*)d_in[33];

    char* ws = (char*)d_ws;
    float*    accb  = (float*)ws;                   // 32,000,000 B
    float*    alpha = (float*)(ws + 32000000);      // 800,000 B
    unsigned* nmax  = (unsigned*)(ws + 32800000);   // 160,000 B
    float*    nden  = (float*)(ws + 32960000);      // 160,000 B
    int*      dtf   = (int*)(ws + 33120000);        // 4 B

    k_detect<<<1, 64, 0, stream>>>(edge_dist, dtf);
    k_fill<<<(NNODES * 1600 + 255) / 256, 256, 0, stream>>>(accb, nden, nmax);

    k_alpha<true><<<EDGES, 256, 0, stream>>>(
        node_feats, edge_dist, wigner, emb_s, emb_r,
        rw1, rb1, rl1s, rl1b, rw2, rb2, rl2s, rl2b, rw3, rb3,
        c1w0, c1b0, an_s, an_b, adot, species, senders, receivers, dtf,
        alpha, nmax);
    k_alpha<false><<<EDGES, 256, 0, stream>>>(
        node_feats, edge_dist, wigner, emb_s, emb_r,
        rw1, rb1, rl1s, rl1b, rw2, rb2, rl2s, rl2b, rw3, rb3,
        c1w0, c1b0, an_s, an_b, adot, species, senders, receivers, dtf,
        alpha, nmax);

    k_exp<<<(EDGES * 8 + 255) / 256, 256, 0, stream>>>(receivers, nmax, alpha, nden);

    k_mega2<true><<<NBLK, 256, 0, stream>>>(
        node_feats, edge_dist, wigner, wigner_inv, to_grid, from_grid, emb_s, emb_r,
        rw1, rb1, rl1s, rl1b, rw2, rb2, rl2s, rl2b, rw3, rb3,
        c1w0, c1b0, c1w1, c1w2, c2w0, c2b0, c2w1, c2w2, proj_w,
        species, senders, receivers, dtf, alpha, nden, accb);
    k_mega2<false><<<NBLK, 256, 0, stream>>>(
        node_feats, edge_dist, wigner, wigner_inv, to_grid, from_grid, emb_s, emb_r,
        rw1, rb1, rl1s, rl1b, rw2, rb2, rl2s, rl2b, rw3, rb3,
        c1w0, c1b0, c1w1, c1w2, c2w0, c2b0, c2w1, c2w2, proj_w,
        species, senders, receivers, dtf, alpha, nden, accb);

    k_out<true><<<(NNODES * 1600 + 255) / 256, 256, 0, stream>>>(accb, proj_b, d_out, dtf);
    k_out<false><<<(NNODES * 1600 + 255) / 256, 256, 0, stream>>>(accb, proj_b, d_out, dtf);
}

// Round 2
// 4842.542 us; speedup vs baseline: 1.6365x; 1.1520x over previous
//
#include <hip/hip_runtime.h>
#include <hip/hip_bf16.h>

using bf16 = __hip_bfloat16;

#define EDGES 25000
#define NNODES 5000
#define EPB 4
#define NBLK (EDGES / EPB)

__device__ __forceinline__ float sigmf(float x) { return 1.0f / (1.0f + expf(-x)); }

template<bool BF>
__device__ __forceinline__ float LD1(const void* p, size_t i) {
    if (BF) return __bfloat162float(((const bf16*)p)[i]);
    else    return ((const float*)p)[i];
}

template<bool BF>
__device__ __forceinline__ float4 LD4(const void* p, size_t i) {
    if (BF) {
        ushort4 u = *reinterpret_cast<const ushort4*>((const bf16*)p + i);
        float4 r;
        r.x = __uint_as_float((unsigned)u.x << 16);
        r.y = __uint_as_float((unsigned)u.y << 16);
        r.z = __uint_as_float((unsigned)u.z << 16);
        r.w = __uint_as_float((unsigned)u.w << 16);
        return r;
    } else {
        return *reinterpret_cast<const float4*>((const float*)p + i);
    }
}

__device__ __forceinline__ void fma4(float4& a, float s, const float4& w) {
    a.x += s * w.x; a.y += s * w.y; a.z += s * w.z; a.w += s * w.w;
}

__device__ __forceinline__ void silu4(float4& a) {
    a.x *= sigmf(a.x); a.y *= sigmf(a.y); a.z *= sigmf(a.z); a.w *= sigmf(a.w);
}

// monotone float<->uint encoding for atomicMax on floats
__device__ __forceinline__ unsigned encF(float f) {
    unsigned b = __float_as_uint(f);
    return (b & 0x80000000u) ? ~b : (b | 0x80000000u);
}
__device__ __forceinline__ float decF(unsigned e) {
    unsigned b = (e & 0x80000000u) ? (e ^ 0x80000000u) : ~e;
    return __uint_as_float(b);
}
#define ENC_NEGINF 0x007FFFFFu

// ---------------- dtype detector ----------------
__global__ void k_detect(const void* edge_dist, int* flag) {
    if (threadIdx.x == 0 && blockIdx.x == 0) {
        const bf16* p = (const bf16*)edge_dist;
        int ok = 1;
        for (int i = 0; i < 256; i++) {
            float v = __bfloat162float(p[i]);
            if (!(v >= 0.0f && v <= 1.0f)) { ok = 0; break; }
        }
        *flag = ok;
    }
}

// ---------------- fill ----------------
__global__ void k_fill(float* accb, float* nden, unsigned* nmax) {
    int tid = blockIdx.x * 256 + threadIdx.x;
    if (tid < NNODES * 1600) accb[tid] = 0.0f;
    if (tid < NNODES * 8) { nden[tid] = 0.0f; nmax[tid] = ENC_NEGINF; }
}

// ---------------- alpha prepass: EPB=4, shared weights ----------------
// LDS floats: XE[768]@0 T1@768 H1@1024 T2@1280 H2@1536
// rad0[2560]@1792 x0[2560]@4352 R[4224]@6912 (X=R, WG=R+3200 | Y=R)
// extraA[1024]@11136 -> total 12160 floats = 48640 B -> 3 blocks/CU
template<bool BF>
__global__ __launch_bounds__(256, 3) void k_alpha(
    const void* __restrict__ node_feats, const void* __restrict__ edge_dist,
    const void* __restrict__ wigner, const void* __restrict__ emb_s,
    const void* __restrict__ emb_r,
    const void* __restrict__ rw1, const void* __restrict__ rb1,
    const void* __restrict__ rl1s, const void* __restrict__ rl1b,
    const void* __restrict__ rw2, const void* __restrict__ rb2,
    const void* __restrict__ rl2s, const void* __restrict__ rl2b,
    const void* __restrict__ rw3, const void* __restrict__ rb3,
    const void* __restrict__ c1w0, const void* __restrict__ c1b0,
    const void* __restrict__ an_s, const void* __restrict__ an_b,
    const void* __restrict__ adot,
    const int* __restrict__ species, const int* __restrict__ senders,
    const int* __restrict__ receivers, const int* __restrict__ dtf,
    float* __restrict__ alpha_out, unsigned* __restrict__ nmax)
{
    if ((*dtf != 0) != BF) return;
    __shared__ __align__(16) float sm[12160];
    float* XE   = sm;
    float* T1   = sm + 768;
    float* H1   = sm + 1024;
    float* T2   = sm + 1280;
    float* H2   = sm + 1536;
    float* rad0 = sm + 1792;
    float* x0   = sm + 4352;
    float* R    = sm + 6912;
    float* extraA = sm + 11136;

    const int t = threadIdx.x;
    const int e0 = blockIdx.x * EPB;
    const int eg = t >> 6, tt = t & 63;

    // ---- XE gather (edge-parallel) ----
    {
        int ee = e0 + eg;
        XE[eg * 192 + tt]       = LD1<BF>(edge_dist, (size_t)ee * 64 + tt);
        XE[eg * 192 + 64 + tt]  = LD1<BF>(emb_s, (size_t)species[senders[ee]] * 64 + tt);
        XE[eg * 192 + 128 + tt] = LD1<BF>(emb_r, (size_t)species[receivers[ee]] * 64 + tt);
    }
    __syncthreads();
    // ---- radial MLP (edge-parallel: 64 threads per edge) ----
    {
        float a = LD1<BF>(rb1, tt);
        #pragma unroll 4
        for (int k = 0; k < 192; k++) a += XE[eg * 192 + k] * LD1<BF>(rw1, k * 64 + tt);
        T1[eg * 64 + tt] = a;
    }
    __syncthreads();
    {
        float mu = 0.f;
        for (int k = 0; k < 64; k++) mu += T1[eg * 64 + k];
        mu *= (1.f / 64.f);
        float var = 0.f;
        for (int k = 0; k < 64; k++) { float d = T1[eg * 64 + k] - mu; var += d * d; }
        float xn = (T1[eg * 64 + tt] - mu) * rsqrtf(var * (1.f / 64.f) + 1e-6f) * LD1<BF>(rl1s, tt) + LD1<BF>(rl1b, tt);
        H1[eg * 64 + tt] = xn * sigmf(xn);
    }
    __syncthreads();
    {
        float a = LD1<BF>(rb2, tt);
        #pragma unroll 4
        for (int k = 0; k < 64; k++) a += H1[eg * 64 + k] * LD1<BF>(rw2, k * 64 + tt);
        T2[eg * 64 + tt] = a;
    }
    __syncthreads();
    {
        float mu = 0.f;
        for (int k = 0; k < 64; k++) mu += T2[eg * 64 + k];
        mu *= (1.f / 64.f);
        float var = 0.f;
        for (int k = 0; k < 64; k++) { float d = T2[eg * 64 + k] - mu; var += d * d; }
        float xn = (T2[eg * 64 + tt] - mu) * rsqrtf(var * (1.f / 64.f) + 1e-6f) * LD1<BF>(rl2s, tt) + LD1<BF>(rl2b, tt);
        H2[eg * 64 + tt] = xn * sigmf(xn);
    }
    __syncthreads();
    // ---- rad0: first 640 outputs of rad, weights shared across 4 edges ----
    if (t < 160) {
        int j0 = t * 4;
        float4 acc[EPB];
        float4 bv = LD4<BF>(rb3, j0);
        #pragma unroll
        for (int e = 0; e < EPB; e++) acc[e] = bv;
        #pragma unroll 4
        for (int k = 0; k < 64; k++) {
            float4 w = LD4<BF>(rw3, (size_t)k * 1536 + j0);
            #pragma unroll
            for (int e = 0; e < EPB; e++) fma4(acc[e], H2[e * 64 + k], w);
        }
        #pragma unroll
        for (int e = 0; e < EPB; e++) *(float4*)&rad0[e * 640 + j0] = acc[e];
    }
    __syncthreads();
    // ---- per-edge: X gather + rotate rows 0..4 + rad scale ----
    {
        float* X  = R;
        float* WG = R + 3200;
        for (int e = 0; e < EPB; e++) {
            int s_ = senders[e0 + e], r_ = receivers[e0 + e];
            for (int q = t; q < 800; q += 256) {
                int k = q >> 5, c0 = (q & 31) * 4;
                float4 v = (c0 < 64) ? LD4<BF>(node_feats, (size_t)s_ * 1600 + k * 64 + c0)
                                     : LD4<BF>(node_feats, (size_t)r_ * 1600 + k * 64 + (c0 - 64));
                *(float4*)&X[q * 4] = v;
            }
            for (int i = t; i < 125; i += 256) WG[i] = LD1<BF>(wigner, (size_t)(e0 + e) * 475 + i);
            __syncthreads();
            if (t < 160) {
                int m = t >> 5, c0 = (t & 31) * 4;
                float4 acc = make_float4(0.f, 0.f, 0.f, 0.f);
                #pragma unroll
                for (int k = 0; k < 25; k++) fma4(acc, WG[m * 25 + k], *(const float4*)&X[k * 128 + c0]);
                float4 rv = *(const float4*)&rad0[e * 640 + t * 4];
                acc.x *= rv.x; acc.y *= rv.y; acc.z *= rv.z; acc.w *= rv.w;
                *(float4*)&x0[e * 640 + t * 4] = acc;
            }
            __syncthreads();
        }
    }
    // ---- alpha matmul: cols [320,576), k split 4 ways, weights shared ----
    {
        float* Y = R;
        int col = t & 63, kq = t >> 6;
        int j0 = 320 + col * 4;
        int ibase = kq * 160;
        float4 acc[EPB];
        #pragma unroll
        for (int e = 0; e < EPB; e++) acc[e] = make_float4(0.f, 0.f, 0.f, 0.f);
        #pragma unroll 4
        for (int k = 0; k < 160; k++) {
            float4 w = LD4<BF>(c1w0, (size_t)(ibase + k) * 640 + j0);
            #pragma unroll
            for (int e = 0; e < EPB; e++) fma4(acc[e], x0[e * 640 + ibase + k], w);
        }
        __syncthreads();  // R (X/WG) dead; Y overlays
        #pragma unroll
        for (int e = 0; e < EPB; e++) *(float4*)&Y[(e * 256 + kq * 64 + col) * 4] = acc[e];
        __syncthreads();
        {
            int e = t >> 6, c = t & 63;
            float4 s = LD4<BF>(c1b0, 320 + c * 4);
            #pragma unroll
            for (int q = 0; q < 4; q++) {
                float4 v = *(const float4*)&Y[(e * 256 + q * 64 + c) * 4];
                s.x += v.x; s.y += v.y; s.z += v.z; s.w += v.w;
            }
            *(float4*)&extraA[e * 256 + c * 4] = s;
        }
    }
    __syncthreads();
    if (t < 32) {
        int e = t >> 3, h = t & 7;
        float mu = 0.0f;
        for (int k = 0; k < 32; k++) mu += extraA[e * 256 + h * 32 + k];
        mu *= (1.0f / 32.0f);
        float var = 0.0f;
        for (int k = 0; k < 32; k++) { float d = extraA[e * 256 + h * 32 + k] - mu; var += d * d; }
        float rs = rsqrtf(var * (1.0f / 32.0f) + 1e-6f);
        float logit = 0.0f;
        for (int k = 0; k < 32; k++) {
            float xn = (extraA[e * 256 + h * 32 + k] - mu) * rs * LD1<BF>(an_s, k) + LD1<BF>(an_b, k);
            float slr = 0.6f * xn + 0.4f * xn * (2.0f * sigmf(xn) - 1.0f);
            logit += slr * LD1<BF>(adot, h * 32 + k);
        }
        int r = receivers[e0 + e];
        alpha_out[(size_t)(e0 + e) * 8 + h] = logit;
        atomicMax(&nmax[r * 8 + h], encF(logit));
    }
}

// ---------------- exp + denom ----------------
__global__ void k_exp(const int* __restrict__ receivers, const unsigned* __restrict__ nmax,
                      float* __restrict__ alpha, float* __restrict__ nden) {
    int tid = blockIdx.x * 256 + threadIdx.x;
    if (tid >= EDGES * 8) return;
    int e = tid >> 3, h = tid & 7;
    int r = receivers[e];
    float m = decF(nmax[r * 8 + h]);
    float ex = expf(alpha[tid] - m);
    alpha[tid] = ex;
    atomicAdd(&nden[r * 8 + h], ex);
}

// ---------------- mega2: 4 edges per block ----------------
// LDS map (floats, total 19744 = 77.1 KB -> 2 blocks/CU):
//   Q   [0,9728)      : EF1[e][2432] (P2-P3) | G(6400)+S2(2432) (P4) | EF3[e][2432] (P5-P7)
//   C   [9728,14592)  : P1 scratch | P2 X(3200)+wg(480) | EF2[e][1216] (P3-P4)
//                       | P5 y-staging | P7 WV[e][480]+EO(6656)
//   RAD [13408,19552) : radial out [e][1536] (live P1-P2 only)
//   YF  [14592,19456) : P3 y-staging | FEATS[e][1216] (P4-P5) | P7 EO tail
//   GAT [19456,19712) : gating [e][64] (P3-P4)
//   ALs [19712,19744) : alpha scale [e][8] (P7)
template<bool BF>
__global__ __launch_bounds__(256, 2) void k_mega2(
    const void* __restrict__ node_feats, const void* __restrict__ edge_dist,
    const void* __restrict__ wigner, const void* __restrict__ wigner_inv,
    const void* __restrict__ to_grid, const void* __restrict__ from_grid,
    const void* __restrict__ emb_s, const void* __restrict__ emb_r,
    const void* __restrict__ rw1, const void* __restrict__ rb1,
    const void* __restrict__ rl1s, const void* __restrict__ rl1b,
    const void* __restrict__ rw2, const void* __restrict__ rb2,
    const void* __restrict__ rl2s, const void* __restrict__ rl2b,
    const void* __restrict__ rw3, const void* __restrict__ rb3,
    const void* __restrict__ c1w0, const void* __restrict__ c1b0,
    const void* __restrict__ c1w1, const void* __restrict__ c1w2,
    const void* __restrict__ c2w0, const void* __restrict__ c2b0,
    const void* __restrict__ c2w1, const void* __restrict__ c2w2,
    const void* __restrict__ proj_w,
    const int* __restrict__ species, const int* __restrict__ senders,
    const int* __restrict__ receivers, const int* __restrict__ dtf,
    const float* __restrict__ alpha, const float* __restrict__ nden,
    float* __restrict__ accb)
{
    if ((*dtf != 0) != BF) return;
    __shared__ __align__(16) float sm[19744];
    float* Q   = sm;
    float* C   = sm + 9728;
    float* RAD = sm + 13408;
    float* YF  = sm + 14592;
    float* GAT = sm + 19456;
    float* ALs = sm + 19712;

    const int t = threadIdx.x;
    const int e0 = blockIdx.x * EPB;
    int snd[EPB], rcv[EPB];
    #pragma unroll
    for (int e = 0; e < EPB; e++) { snd[e] = senders[e0 + e]; rcv[e] = receivers[e0 + e]; }

    // ---- P1: radial MLP (edge-parallel 4x64; rw3 weights shared) ----
    {
        float* XE = C;
        float* T1 = C + 768;
        float* H1 = C + 1024;
        float* T2 = C + 1280;
        float* H2 = C + 1536;
        const int eg = t >> 6, tt = t & 63;
        {
            int ee = e0 + eg;
            XE[eg * 192 + tt]       = LD1<BF>(edge_dist, (size_t)ee * 64 + tt);
            XE[eg * 192 + 64 + tt]  = LD1<BF>(emb_s, (size_t)species[senders[ee]] * 64 + tt);
            XE[eg * 192 + 128 + tt] = LD1<BF>(emb_r, (size_t)species[receivers[ee]] * 64 + tt);
        }
        __syncthreads();
        {
            float a = LD1<BF>(rb1, tt);
            #pragma unroll 4
            for (int k = 0; k < 192; k++) a += XE[eg * 192 + k] * LD1<BF>(rw1, k * 64 + tt);
            T1[eg * 64 + tt] = a;
        }
        __syncthreads();
        {
            float mu = 0.f;
            for (int k = 0; k < 64; k++) mu += T1[eg * 64 + k];
            mu *= (1.f / 64.f);
            float var = 0.f;
            for (int k = 0; k < 64; k++) { float d = T1[eg * 64 + k] - mu; var += d * d; }
            float xn = (T1[eg * 64 + tt] - mu) * rsqrtf(var * (1.f / 64.f) + 1e-6f) * LD1<BF>(rl1s, tt) + LD1<BF>(rl1b, tt);
            H1[eg * 64 + tt] = xn * sigmf(xn);
        }
        __syncthreads();
        {
            float a = LD1<BF>(rb2, tt);
            #pragma unroll 4
            for (int k = 0; k < 64; k++) a += H1[eg * 64 + k] * LD1<BF>(rw2, k * 64 + tt);
            T2[eg * 64 + tt] = a;
        }
        __syncthreads();
        {
            float mu = 0.f;
            for (int k = 0; k < 64; k++) mu += T2[eg * 64 + k];
            mu *= (1.f / 64.f);
            float var = 0.f;
            for (int k = 0; k < 64; k++) { float d = T2[eg * 64 + k] - mu; var += d * d; }
            float xn = (T2[eg * 64 + tt] - mu) * rsqrtf(var * (1.f / 64.f) + 1e-6f) * LD1<BF>(rl2s, tt) + LD1<BF>(rl2b, tt);
            H2[eg * 64 + tt] = xn * sigmf(xn);
        }
        __syncthreads();
        for (int qq = t; qq < 384; qq += 256) {
            int j0 = qq * 4;
            float4 acc[EPB];
            float4 bv = LD4<BF>(rb3, j0);
            #pragma unroll
            for (int e = 0; e < EPB; e++) acc[e] = bv;
            #pragma unroll 4
            for (int k = 0; k < 64; k++) {
                float4 w = LD4<BF>(rw3, (size_t)k * 1536 + j0);
                #pragma unroll
                for (int e = 0; e < EPB; e++) fma4(acc[e], H2[e * 64 + k], w);
            }
            #pragma unroll
            for (int e = 0; e < EPB; e++) *(float4*)&RAD[e * 1536 + j0] = acc[e];
        }
        __syncthreads();
    }

    // ---- P2: gather + wigner rotate + rad scale (per edge sequential) ----
    {
        float* X  = C;          // 3200
        float* WG = C + 3200;   // 480
        for (int e = 0; e < EPB; e++) {
            int s_ = senders[e0 + e], r_ = receivers[e0 + e];
            for (int q = t; q < 800; q += 256) {
                int k = q >> 5, c0 = (q & 31) * 4;
                float4 v = (c0 < 64) ? LD4<BF>(node_feats, (size_t)s_ * 1600 + k * 64 + c0)
                                     : LD4<BF>(node_feats, (size_t)r_ * 1600 + k * 64 + (c0 - 64));
                *(float4*)&X[q * 4] = v;
            }
            for (int i = t; i < 475; i += 256) WG[i] = LD1<BF>(wigner, (size_t)(e0 + e) * 475 + i);
            __syncthreads();
            for (int q = t; q < 608; q += 256) {
                int m = q >> 5, c0 = (q & 31) * 4;
                float4 acc = make_float4(0.f, 0.f, 0.f, 0.f);
                #pragma unroll
                for (int k = 0; k < 25; k++) fma4(acc, WG[m * 25 + k], *(const float4*)&X[k * 128 + c0]);
                int ri0;
                if (m < 5)       ri0 = m * 128 + c0;
                else if (m < 13) ri0 = 640 + ((m - 5) & 3) * 128 + c0;
                else             ri0 = 1152 + ((m - 13) % 3) * 128 + c0;
                float4 rv = *(const float4*)&RAD[e * 1536 + ri0];
                acc.x *= rv.x; acc.y *= rv.y; acc.z *= rv.z; acc.w *= rv.w;
                *(float4*)&Q[e * 2432 + q * 4] = acc;
            }
            __syncthreads();
        }
    }

    // ---- P3: conv1 (weights shared across 4 edges) ----
    float4 ra[EPB], rb[EPB];
    {
        float* EF2 = C;
        // m0 (threads 0..95) || m1 (threads 128..255)
        if (t < 96) {
            int jq = (t < 80) ? t : (144 + (t - 80));
            int j0 = jq * 4;
            float4 acc[EPB];
            float4 bv = LD4<BF>(c1b0, j0);
            #pragma unroll
            for (int e = 0; e < EPB; e++) acc[e] = bv;
            #pragma unroll 4
            for (int i = 0; i < 640; i++) {
                float4 w = LD4<BF>(c1w0, (size_t)i * 640 + j0);
                #pragma unroll
                for (int e = 0; e < EPB; e++) fma4(acc[e], Q[e * 2432 + i], w);
            }
            if (t < 80) {
                #pragma unroll
                for (int e = 0; e < EPB; e++) *(float4*)&EF2[e * 1216 + j0] = acc[e];
            } else {
                #pragma unroll
                for (int e = 0; e < EPB; e++) *(float4*)&GAT[e * 64 + (t - 80) * 4] = acc[e];
            }
        } else if (t >= 128) {
            int j0 = (t - 128) * 4;  // 0..508
            #pragma unroll
            for (int e = 0; e < EPB; e++) { ra[e] = make_float4(0,0,0,0); rb[e] = make_float4(0,0,0,0); }
            #pragma unroll 4
            for (int i = 0; i < 512; i++) {
                float4 w = LD4<BF>(c1w1, (size_t)i * 512 + j0);
                #pragma unroll
                for (int e = 0; e < EPB; e++) {
                    fma4(ra[e], Q[e * 2432 + 640 + i], w);
                    fma4(rb[e], Q[e * 2432 + 1152 + i], w);
                }
            }
            if (j0 >= 256) {  // threads 192..255 stage upper halves
                #pragma unroll
                for (int e = 0; e < EPB; e++) {
                    *(float4*)&YF[e * 256 + (j0 - 256)] = ra[e];
                    *(float4*)&YF[1024 + e * 256 + (j0 - 256)] = rb[e];
                }
            }
        }
        __syncthreads();
        if (t >= 128 && t < 192) {  // m1 combine
            int j0 = (t - 128) * 4;
            #pragma unroll
            for (int e = 0; e < EPB; e++) {
                float4 y0u = *(const float4*)&YF[e * 256 + j0];
                float4 y1u = *(const float4*)&YF[1024 + e * 256 + j0];
                float4 r, im;
                r.x = ra[e].x - y1u.x; r.y = ra[e].y - y1u.y; r.z = ra[e].z - y1u.z; r.w = ra[e].w - y1u.w;
                im.x = rb[e].x + y0u.x; im.y = rb[e].y + y0u.y; im.z = rb[e].z + y0u.z; im.w = rb[e].w + y0u.w;
                *(float4*)&EF2[e * 1216 + 320 + j0] = r;
                *(float4*)&EF2[e * 1216 + 576 + j0] = im;
            }
        }
        __syncthreads();
        // m2 (threads 0..95)
        if (t < 96) {
            int j0 = t * 4;  // 0..380
            #pragma unroll
            for (int e = 0; e < EPB; e++) { ra[e] = make_float4(0,0,0,0); rb[e] = make_float4(0,0,0,0); }
            #pragma unroll 4
            for (int i = 0; i < 384; i++) {
                float4 w = LD4<BF>(c1w2, (size_t)i * 384 + j0);
                #pragma unroll
                for (int e = 0; e < EPB; e++) {
                    fma4(ra[e], Q[e * 2432 + 1664 + i], w);
                    fma4(rb[e], Q[e * 2432 + 2048 + i], w);
                }
            }
            if (j0 >= 192) {  // threads 48..95 stage upper halves
                #pragma unroll
                for (int e = 0; e < EPB; e++) {
                    *(float4*)&YF[e * 192 + (j0 - 192)] = ra[e];
                    *(float4*)&YF[768 + e * 192 + (j0 - 192)] = rb[e];
                }
            }
        }
        __syncthreads();
        if (t < 48) {  // m2 combine
            int j0 = t * 4;
            #pragma unroll
            for (int e = 0; e < EPB; e++) {
                float4 y0u = *(const float4*)&YF[e * 192 + j0];
                float4 y1u = *(const float4*)&YF[768 + e * 192 + j0];
                float4 r, im;
                r.x = ra[e].x - y1u.x; r.y = ra[e].y - y1u.y; r.z = ra[e].z - y1u.z; r.w = ra[e].w - y1u.w;
                im.x = rb[e].x + y0u.x; im.y = rb[e].y + y0u.y; im.z = rb[e].z + y0u.z; im.w = rb[e].w + y0u.w;
                *(float4*)&EF2[e * 1216 + 832 + j0] = r;
                *(float4*)&EF2[e * 1216 + 1024 + j0] = im;
            }
        }
        __syncthreads();
    }

    // ---- P4: grid nonlinearity (full 100-point grid, balanced from_grid) ----
    {
        float* FE  = YF;        // FEATS [e][1216]
        float* G   = Q;         // 100 x 64 = 6400
        float* S2  = Q + 6400;  // 608 f4 = 2432
        float* EF2 = C;
        for (int e = 0; e < EPB; e++) {
            for (int idx = t; idx < 1600; idx += 256) {
                int gi = idx >> 4, c0 = (idx & 15) * 4;
                float4 acc = make_float4(0.f, 0.f, 0.f, 0.f);
                #pragma unroll
                for (int m = 0; m < 19; m++)
                    fma4(acc, LD1<BF>(to_grid, gi * 19 + m),
                         *(const float4*)&EF2[e * 1216 + m * 64 + c0]);
                silu4(acc);
                *(float4*)&G[gi * 64 + c0] = acc;
            }
            __syncthreads();
            for (int idx = t; idx < 608; idx += 256) {
                int m = idx >> 5, cq = (idx >> 1) & 15, h = idx & 1, c0 = cq * 4;
                int g0 = h * 50;
                float4 acc = make_float4(0.f, 0.f, 0.f, 0.f);
                #pragma unroll 5
                for (int gi = 0; gi < 50; gi++)
                    fma4(acc, LD1<BF>(from_grid, (g0 + gi) * 19 + m),
                         *(const float4*)&G[(g0 + gi) * 64 + c0]);
                *(float4*)&S2[idx * 4] = acc;
            }
            __syncthreads();
            for (int idx = t; idx < 304; idx += 256) {
                int m = idx >> 4, cq = idx & 15;
                int pb = (m * 32 + cq * 2) * 4;
                float4 a = *(const float4*)&S2[pb];
                float4 b = *(const float4*)&S2[pb + 4];
                a.x += b.x; a.y += b.y; a.z += b.z; a.w += b.w;
                *(float4*)&FE[e * 1216 + m * 64 + cq * 4] = a;
            }
            __syncthreads();
        }
        if (t < 64) {
            #pragma unroll
            for (int e = 0; e < EPB; e++) { float x = GAT[e * 64 + t]; FE[e * 1216 + t] = x * sigmf(x); }
        }
        __syncthreads();
    }

    // ---- P5: conv2 -> EF3 (in Q; weights shared across 4 edges) ----
    {
        float* FE = YF;
        if (t < 160) {  // m0: 640 outs, k=320
            int j0 = t * 4;
            float4 acc[EPB];
            float4 bv = LD4<BF>(c2b0, j0);
            #pragma unroll
            for (int e = 0; e < EPB; e++) acc[e] = bv;
            #pragma unroll 4
            for (int i = 0; i < 320; i++) {
                float4 w = LD4<BF>(c2w0, (size_t)i * 640 + j0);
                #pragma unroll
                for (int e = 0; e < EPB; e++) fma4(acc[e], FE[e * 1216 + i], w);
            }
            #pragma unroll
            for (int e = 0; e < EPB; e++) *(float4*)&Q[e * 2432 + j0] = acc[e];
        }
        {  // m1: 1024 cols, k=256, all threads
            int j0 = t * 4;
            #pragma unroll
            for (int e = 0; e < EPB; e++) { ra[e] = make_float4(0,0,0,0); rb[e] = make_float4(0,0,0,0); }
            #pragma unroll 4
            for (int i = 0; i < 256; i++) {
                float4 w = LD4<BF>(c2w1, (size_t)i * 1024 + j0);
                #pragma unroll
                for (int e = 0; e < EPB; e++) {
                    fma4(ra[e], FE[e * 1216 + 320 + i], w);
                    fma4(rb[e], FE[e * 1216 + 576 + i], w);
                }
            }
            if (j0 >= 512) {
                #pragma unroll
                for (int e = 0; e < EPB; e++) {
                    *(float4*)&C[e * 512 + (j0 - 512)] = ra[e];
                    *(float4*)&C[2048 + e * 512 + (j0 - 512)] = rb[e];
                }
            }
        }
        __syncthreads();
        if (t < 128) {  // m1 combine
            int j0 = t * 4;
            #pragma unroll
            for (int e = 0; e < EPB; e++) {
                float4 y0u = *(const float4*)&C[e * 512 + j0];
                float4 y1u = *(const float4*)&C[2048 + e * 512 + j0];
                float4 r, im;
                r.x = ra[e].x - y1u.x; r.y = ra[e].y - y1u.y; r.z = ra[e].z - y1u.z; r.w = ra[e].w - y1u.w;
                im.x = rb[e].x + y0u.x; im.y = rb[e].y + y0u.y; im.z = rb[e].z + y0u.z; im.w = rb[e].w + y0u.w;
                *(float4*)&Q[e * 2432 + 640 + j0] = r;
                *(float4*)&Q[e * 2432 + 1152 + j0] = im;
            }
        }
        __syncthreads();
        if (t < 192) {  // m2: 768 cols, k=192
            int j0 = t * 4;
            #pragma unroll
            for (int e = 0; e < EPB; e++) { ra[e] = make_float4(0,0,0,0); rb[e] = make_float4(0,0,0,0); }
            #pragma unroll 4
            for (int i = 0; i < 192; i++) {
                float4 w = LD4<BF>(c2w2, (size_t)i * 768 + j0);
                #pragma unroll
                for (int e = 0; e < EPB; e++) {
                    fma4(ra[e], FE[e * 1216 + 832 + i], w);
                    fma4(rb[e], FE[e * 1216 + 1024 + i], w);
                }
            }
            if (j0 >= 384) {
                #pragma unroll
                for (int e = 0; e < EPB; e++) {
                    *(float4*)&C[e * 384 + (j0 - 384)] = ra[e];
                    *(float4*)&C[1536 + e * 384 + (j0 - 384)] = rb[e];
                }
            }
        }
        __syncthreads();
        if (t < 96) {  // m2 combine
            int j0 = t * 4;
            #pragma unroll
            for (int e = 0; e < EPB; e++) {
                float4 y0u = *(const float4*)&C[e * 384 + j0];
                float4 y1u = *(const float4*)&C[1536 + e * 384 + j0];
                float4 r, im;
                r.x = ra[e].x - y1u.x; r.y = ra[e].y - y1u.y; r.z = ra[e].z - y1u.z; r.w = ra[e].w - y1u.w;
                im.x = rb[e].x + y0u.x; im.y = rb[e].y + y0u.y; im.z = rb[e].z + y0u.z; im.w = rb[e].w + y0u.w;
                *(float4*)&Q[e * 2432 + 1664 + j0] = r;
                *(float4*)&Q[e * 2432 + 2048 + j0] = im;
            }
        }
        __syncthreads();
    }

    // ---- P7: wigner_inv rotate + alpha + fused proj (2 k-chunks {13,12}) ----
    {
        float* WV = C;           // [e][480]
        float* EO = C + 1920;    // up to 13*512 = 6656 floats
        if (t < 32) {
            int h = t & 7;
            int ee = e0 + (t >> 3);
            ALs[t] = alpha[(size_t)ee * 8 + h] / (nden[(size_t)receivers[ee] * 8 + h] + 1e-16f);
        }
        for (int i = t; i < 1900; i += 256) {
            int e = i / 475, j = i - e * 475;
            WV[e * 480 + j] = LD1<BF>(wigner_inv, (size_t)(e0 + e) * 475 + j);
        }
        __syncthreads();
        for (int kb = 0; kb < 25; kb += 13) {
            const int nk = (kb == 0) ? 13 : 12;
            // EO: flattened over (idx, e), e in low 2 bits -> conflict-free stores
            for (int u = t; u < nk * 128; u += 256) {
                int e = u & 3, idx = u >> 2;
                int ki = idx >> 5, c0 = (idx & 31) * 4;
                int k = kb + ki;
                float4 acc = make_float4(0.f, 0.f, 0.f, 0.f);
                #pragma unroll
                for (int m = 0; m < 19; m++)
                    fma4(acc, WV[e * 480 + k * 19 + m], *(const float4*)&Q[e * 2432 + m * 128 + c0]);
                float al = ALs[e * 8 + (c0 >> 4)];
                int b = (ki * 128 + c0) * 4 + e;
                EO[b + 0]  = acc.x * al;
                EO[b + 4]  = acc.y * al;
                EO[b + 8]  = acc.z * al;
                EO[b + 12] = acc.w * al;
            }
            __syncthreads();
            if (t < nk * 16) {
                int ki = t >> 4, o0 = (t & 15) * 4;
                int k = kb + ki;
                int l = (k == 0) ? 0 : (k < 4) ? 1 : (k < 9) ? 2 : (k < 16) ? 3 : 4;
                float4 pa0 = make_float4(0,0,0,0), pa1 = pa0, pa2 = pa0, pa3 = pa0;
                const float* eob = &EO[ki * 512];
                #pragma unroll 4
                for (int c = 0; c < 128; c++) {
                    float4 pw = LD4<BF>(proj_w, (size_t)l * 8192 + (size_t)c * 64 + o0);
                    float4 ev = *(const float4*)&eob[c * 4];
                    fma4(pa0, ev.x, pw); fma4(pa1, ev.y, pw);
                    fma4(pa2, ev.z, pw); fma4(pa3, ev.w, pw);
                }
                float* d0 = &accb[(size_t)rcv[0] * 1600 + k * 64 + o0];
                atomicAdd(d0 + 0, pa0.x); atomicAdd(d0 + 1, pa0.y);
                atomicAdd(d0 + 2, pa0.z); atomicAdd(d0 + 3, pa0.w);
                float* d1 = &accb[(size_t)rcv[1] * 1600 + k * 64 + o0];
                atomicAdd(d1 + 0, pa1.x); atomicAdd(d1 + 1, pa1.y);
                atomicAdd(d1 + 2, pa1.z); atomicAdd(d1 + 3, pa1.w);
                float* d2 = &accb[(size_t)rcv[2] * 1600 + k * 64 + o0];
                atomicAdd(d2 + 0, pa2.x); atomicAdd(d2 + 1, pa2.y);
                atomicAdd(d2 + 2, pa2.z); atomicAdd(d2 + 3, pa2.w);
                float* d3 = &accb[(size_t)rcv[3] * 1600 + k * 64 + o0];
                atomicAdd(d3 + 0, pa3.x); atomicAdd(d3 + 1, pa3.y);
                atomicAdd(d3 + 2, pa3.z); atomicAdd(d3 + 3, pa3.w);
            }
            __syncthreads();
        }
    }
}

// ---------------- bias + convert ----------------
template<bool BF>
__global__ void k_out(const float* __restrict__ accb, const void* __restrict__ proj_b,
                      void* __restrict__ out, const int* __restrict__ dtf) {
    if ((*dtf != 0) != BF) return;
    int i = blockIdx.x * 256 + threadIdx.x;
    if (i >= NNODES * 1600) return;
    int r = i % 1600;
    int m = r >> 6, o = r & 63;
    float v = accb[i] + ((m == 0) ? LD1<BF>(proj_b, o) : 0.0f);
    if (BF) ((bf16*)out)[i] = __float2bfloat16(v);
    else    ((float*)out)[i] = v;
}

extern "C" void kernel_launch(void* const* d_in, const int* in_sizes, int n_in,
                              void* d_out, int out_size, void* d_ws, size_t ws_size,
                              hipStream_t stream) {
    const void* node_feats = d_in[0];
    const void* edge_dist  = d_in[1];
    const void* wigner     = d_in[2];
    const void* wigner_inv = d_in[3];
    const void* to_grid    = d_in[4];
    const void* from_grid  = d_in[5];
    const void* emb_s      = d_in[6];
    const void* emb_r      = d_in[7];
    const void* rw1  = d_in[8];
    const void* rb1  = d_in[9];
    const void* rl1s = d_in[10];
    const void* rl1b = d_in[11];
    const void* rw2  = d_in[12];
    const void* rb2  = d_in[13];
    const void* rl2s = d_in[14];
    const void* rl2b = d_in[15];
    const void* rw3  = d_in[16];
    const void* rb3  = d_in[17];
    const void* c1w0 = d_in[18];
    const void* c1b0 = d_in[19];
    const void* c1w1 = d_in[20];
    const void* c1w2 = d_in[21];
    const void* c2w0 = d_in[22];
    const void* c2b0 = d_in[23];
    const void* c2w1 = d_in[24];
    const void* c2w2 = d_in[25];
    const void* an_s = d_in[26];
    const void* an_b = d_in[27];
    const void* adot = d_in[28];
    const void* proj_w = d_in[29];
    const void* proj_b = d_in[30];
    const int* species   = (const int*)d_in[31];
    const int* senders   = (const int*)d_in[32];
    const int* receivers = (const int*)d_in[33];

    char* ws = (char*)d_ws;
    float*    accb  = (float*)ws;                   // 32,000,000 B
    float*    alpha = (float*)(ws + 32000000);      // 800,000 B
    unsigned* nmax  = (unsigned*)(ws + 32800000);   // 160,000 B
    float*    nden  = (float*)(ws + 32960000);      // 160,000 B
    int*      dtf   = (int*)(ws + 33120000);        // 4 B

    k_detect<<<1, 64, 0, stream>>>(edge_dist, dtf);
    k_fill<<<(NNODES * 1600 + 255) / 256, 256, 0, stream>>>(accb, nden, nmax);

    k_alpha<true><<<NBLK, 256, 0, stream>>>(
        node_feats, edge_dist, wigner, emb_s, emb_r,
        rw1, rb1, rl1s, rl1b, rw2, rb2, rl2s, rl2b, rw3, rb3,
        c1w0, c1b0, an_s, an_b, adot, species, senders, receivers, dtf,
        alpha, nmax);
    k_alpha<false><<<NBLK, 256, 0, stream>>>(
        node_feats, edge_dist, wigner, emb_s, emb_r,
        rw1, rb1, rl1s, rl1b, rw2, rb2, rl2s, rl2b, rw3, rb3,
        c1w0, c1b0, an_s, an_b, adot, species, senders, receivers, dtf,
        alpha, nmax);

    k_exp<<<(EDGES * 8 + 255) / 256, 256, 0, stream>>>(receivers, nmax, alpha, nden);

    k_mega2<true><<<NBLK, 256, 0, stream>>>(
        node_feats, edge_dist, wigner, wigner_inv, to_grid, from_grid, emb_s, emb_r,
        rw1, rb1, rl1s, rl1b, rw2, rb2, rl2s, rl2b, rw3, rb3,
        c1w0, c1b0, c1w1, c1w2, c2w0, c2b0, c2w1, c2w2, proj_w,
        species, senders, receivers, dtf, alpha, nden, accb);
    k_mega2<false><<<NBLK, 256, 0, stream>>>(
        node_feats, edge_dist, wigner, wigner_inv, to_grid, from_grid, emb_s, emb_r,
        rw1, rb1, rl1s, rl1b, rw2, rb2, rl2s, rl2b, rw3, rb3,
        c1w0, c1b0, c1w1, c1w2, c2w0, c2b0, c2w1, c2w2, proj_w,
        species, senders, receivers, dtf, alpha, nden, accb);

    k_out<true><<<(NNODES * 1600 + 255) / 256, 256, 0, stream>>>(accb, proj_b, d_out, dtf);
    k_out<false><<<(NNODES * 1600 + 255) / 256, 256, 0, stream>>>(accb, proj_b, d_out, dtf);
}